// Round 22
// baseline (100.362 us; speedup 1.0000x reference)
//
#include <hip/hip_runtime.h>
#include <hip/hip_bf16.h>
#include <math.h>

#define NREG 90
#define NN 91
#define JROWS 96
#define STR 100           // A LDS stride (words), fp32 then packed u32 in place
#define NPAIR 4005
#define H1 256
#define H2 256
#define F1 128
#define SPSTR 260         // packed svec/pooled LDS stride (u32)

typedef __bf16 bf16x8 __attribute__((ext_vector_type(8)));
typedef float  f32x4  __attribute__((ext_vector_type(4)));
typedef unsigned int u32x4v __attribute__((ext_vector_type(4)));

__device__ __forceinline__ unsigned int pack_hl(float f) {
    __bf16 h = (__bf16)f;
    __bf16 l = (__bf16)(f - (float)h);
    unsigned short hb = __builtin_bit_cast(unsigned short, h);
    unsigned short lb = __builtin_bit_cast(unsigned short, l);
    return ((unsigned int)lb << 16) | (unsigned int)hb;
}

// ---- one-shot prep: W1/W2/Wo1 MFMA fragments (hi/lo) + pair table ----
__global__ void prep(const float* __restrict__ W1, const float* __restrict__ W2,
                     const float* __restrict__ Wo1,
                     __bf16* __restrict__ Whi, __bf16* __restrict__ Wlo,
                     int* __restrict__ ptab,
                     __bf16* __restrict__ W2fh, __bf16* __restrict__ W2fl,
                     __bf16* __restrict__ Wo1fh, __bf16* __restrict__ Wo1fl) {
    int t = blockIdx.x * 256 + threadIdx.x;       // 0..65535
    if (t < 24576) {                               // W1 frags [16 nt][3 ks][64][8]
        int e  = t & 7;
        int ln = (t >> 3) & 63;
        int g  = t >> 9;
        int nt = g / 3;
        int ks = g - nt * 3;
        int h = nt * 16 + (ln & 15);
        int k = ks * 32 + (ln >> 4) * 8 + e;
        float v = (k < NN) ? W1[h * NN + k] : 0.0f;
        __bf16 hb = (__bf16)v;
        __bf16 lb = (__bf16)(v - (float)hb);
        Whi[t] = hb;
        Wlo[t] = lb;
    }
    {                                              // W2 frags [16 nt][8 ks][64][8]
        int e  = t & 7;
        int ln = (t >> 3) & 63;
        int g2 = t >> 9;
        int nt = g2 >> 3, ks = g2 & 7;
        float v = W2[(nt * 16 + (ln & 15)) * 256 + ks * 32 + (ln >> 4) * 8 + e];
        __bf16 hb = (__bf16)v;
        __bf16 lb = (__bf16)(v - (float)hb);
        W2fh[t] = hb;
        W2fl[t] = lb;
    }
    if (t < 32768) {                               // Wo1 frags [8 nt][8 ks][64][8]
        int e  = t & 7;
        int ln = (t >> 3) & 63;
        int g2 = t >> 9;
        int nt = g2 >> 3, ks = g2 & 7;
        float v = Wo1[(nt * 16 + (ln & 15)) * 256 + ks * 32 + (ln >> 4) * 8 + e];
        __bf16 hb = (__bf16)v;
        __bf16 lb = (__bf16)(v - (float)hb);
        Wo1fh[t] = hb;
        Wo1fl[t] = lb;
    }
    if (t < NPAIR) {
        float disc = 32041.0f - 8.0f * (float)t;
        int i = (int)floorf((179.0f - sqrtf(disc)) * 0.5f);
        if (i < 0) i = 0;
        while (i > 0 && t < i * (179 - i) / 2) --i;
        while (t >= (i + 1) * (178 - i) / 2) ++i;
        int j = i + 1 + (t - i * (179 - i) / 2);
        ptab[t] = (i << 7) | j;
    }
}

// ========== merged kernel (512 thr, 8 waves): build + pack + MFMA -> svec ==========
// A is stored XOR-swizzled: logical col j of row i lives at word j ^ ((i&7)<<2).
// (16B-block XOR; bijective over blocks 0..23; rows stay 16B-aligned)
__global__ __launch_bounds__(512)
void mk_build_gemm(const float* __restrict__ coh,    // [B, 4005]
                   const int*   __restrict__ ptab,
                   const __bf16* __restrict__ Whi,   // [16][3][64][8]
                   const __bf16* __restrict__ Wlo,
                   float* __restrict__ svec_out)     // [B][256]
{
    __shared__ __align__(16) float A[JROWS * STR];   // 38400 B
    __shared__ __align__(16) float dinv[128];
    __shared__ __align__(16) float arow[96];

    const int b = blockIdx.x;
    const int t = threadIdx.x;
    const int w = t >> 6, lane = t & 63;
    const float* cb = coh + (size_t)b * NPAIR;

    // ---- 0) W fragments -> registers EARLY ----
    bf16x8 whi_r[2][3], wlo_r[2][3];
    #pragma unroll
    for (int nt = 0; nt < 2; ++nt)
        #pragma unroll
        for (int ks = 0; ks < 3; ++ks) {
            int idx = (((w * 2 + nt) * 3 + ks) * 64 + lane) * 8;
            whi_r[nt][ks] = *(const bf16x8*)(Whi + idx);
            wlo_r[nt][ks] = *(const bf16x8*)(Wlo + idx);
        }

    // ---- 1) swizzled scatter + diag + supernode + pads + dinv-zero ----
    for (int m4 = t; m4 < NPAIR / 4; m4 += 512) {    // m = 0..4003
        int4 p4 = ((const int4*)ptab)[m4];
        float v0 = cb[4 * m4 + 0];
        float v1 = cb[4 * m4 + 1];
        float v2 = cb[4 * m4 + 2];
        float v3 = cb[4 * m4 + 3];
        int i0 = p4.x >> 7, j0 = p4.x & 127;
        int i1 = p4.y >> 7, j1 = p4.y & 127;
        int i2 = p4.z >> 7, j2 = p4.z & 127;
        int i3 = p4.w >> 7, j3 = p4.w & 127;
        A[i0 * STR + (j0 ^ ((i0 & 7) << 2))] = v0; A[j0 * STR + (i0 ^ ((j0 & 7) << 2))] = v0;
        A[i1 * STR + (j1 ^ ((i1 & 7) << 2))] = v1; A[j1 * STR + (i1 ^ ((j1 & 7) << 2))] = v1;
        A[i2 * STR + (j2 ^ ((i2 & 7) << 2))] = v2; A[j2 * STR + (i2 ^ ((j2 & 7) << 2))] = v2;
        A[i3 * STR + (j3 ^ ((i3 & 7) << 2))] = v3; A[j3 * STR + (i3 ^ ((j3 & 7) << 2))] = v3;
    }
    if (t == 0) {                                    // tail element m = 4004
        int p = ptab[NPAIR - 1];
        int i = p >> 7, j = p & 127;
        float v = cb[NPAIR - 1];
        A[i * STR + (j ^ ((i & 7) << 2))] = v;
        A[j * STR + (i ^ ((j & 7) << 2))] = v;
    }
    if (t < NN) {
        int sw = (t & 7) << 2;
        A[t * STR + (t ^ sw)] = 1.0f;                // diag
        if (t < NREG) {
            A[NREG * STR + (t ^ 8)] = 1.0f;          // supernode row (90&7)<<2 = 8
            A[t * STR + (NREG ^ sw)] = 1.0f;         // supernode col
        }
        A[t * STR + (91 ^ sw)] = 0.0f;               // pad cols 91..95
        A[t * STR + (92 ^ sw)] = 0.0f;
        A[t * STR + (93 ^ sw)] = 0.0f;
        A[t * STR + (94 ^ sw)] = 0.0f;
        A[t * STR + (95 ^ sw)] = 0.0f;
    }
    if (t >= 128 && t < 128 + 5 * 24) {              // pad rows 91..95 (full-row zero)
        int m = t - 128;
        int i = 91 + m / 24;
        int c4 = (m - (m / 24) * 24) * 4;
        *(float4*)&A[i * STR + c4] = make_float4(0.f, 0.f, 0.f, 0.f);
    }
    if (t >= 256 && t < 384) dinv[t - 256] = 0.0f;
    __syncthreads();

    // ---- 2) degree^-1/2 (reads in per-row XORed block order: spreads banks) ----
    if (t < NN) {
        const float4* row = (const float4*)&A[t * STR];
        const int s = t & 7;
        float sx = 0.f, sy = 0.f, sz = 0.f, sw = 0.f;
        #pragma unroll
        for (int q = 0; q < 24; ++q) {
            float4 v = row[q ^ s];
            sx += v.x; sy += v.y; sz += v.z; sw += v.w;
        }
        dinv[t] = 1.0f / sqrtf((sx + sy) + (sz + sw));
    }
    __syncthreads();

    // ---- 3) FUSED: scale + arow save + bf16-pair pack (physical-block walk) ----
    for (int m = t; m < JROWS * 24; m += 512) {
        int i = m / 24;
        int p = m - i * 24;                          // physical block
        int q4 = (p ^ (i & 7)) * 4;                  // logical col base
        float di = dinv[i];
        float4 dj = *(const float4*)&dinv[q4];
        float4 v = *(float4*)&A[i * STR + p * 4];
        v.x *= di * dj.x; v.y *= di * dj.y; v.z *= di * dj.z; v.w *= di * dj.w;
        if (i == NREG) *(float4*)&arow[q4] = v;
        uint4 pk;
        pk.x = pack_hl(v.x); pk.y = pack_hl(v.y);
        pk.z = pack_hl(v.z); pk.w = pack_hl(v.w);
        *(uint4*)&A[i * STR + p * 4] = pk;
    }
    __syncthreads();

    // ---- 4) MFMA: wave w owns n-tiles {2w, 2w+1}; swizzled frag reads ----
    {
        const int lrow = lane & 15, lkg = lane >> 4;
        const int s = lrow & 7;                      // (m*16+lrow)&7 == lrow&7
        const unsigned int* Au = (const unsigned int*)A;

        float sp[2] = {0.f, 0.f};

        #pragma unroll
        for (int m = 0; m < 6; ++m) {
            const uint4* rowp = (const uint4*)(Au + (m * 16 + lrow) * STR);
            bf16x8 ahi[3], alo[3];
            #pragma unroll
            for (int ks = 0; ks < 3; ++ks) {
                int e = ks * 8 + lkg * 2;            // logical 16B-block pair
                uint4 a0 = rowp[e ^ s];
                uint4 a1 = rowp[(e + 1) ^ s];
                u32x4v hw, lw;
                hw[0] = __builtin_amdgcn_perm(a0.y, a0.x, 0x05040100u);
                hw[1] = __builtin_amdgcn_perm(a0.w, a0.z, 0x05040100u);
                hw[2] = __builtin_amdgcn_perm(a1.y, a1.x, 0x05040100u);
                hw[3] = __builtin_amdgcn_perm(a1.w, a1.z, 0x05040100u);
                lw[0] = __builtin_amdgcn_perm(a0.y, a0.x, 0x07060302u);
                lw[1] = __builtin_amdgcn_perm(a0.w, a0.z, 0x07060302u);
                lw[2] = __builtin_amdgcn_perm(a1.y, a1.x, 0x07060302u);
                lw[3] = __builtin_amdgcn_perm(a1.w, a1.z, 0x07060302u);
                ahi[ks] = __builtin_bit_cast(bf16x8, hw);
                alo[ks] = __builtin_bit_cast(bf16x8, lw);
            }
            float aj[4];
            #pragma unroll
            for (int ri = 0; ri < 4; ++ri)
                aj[ri] = arow[m * 16 + lkg * 4 + ri];

            f32x4 acc[2];
            acc[0] = (f32x4){0.f, 0.f, 0.f, 0.f};
            acc[1] = (f32x4){0.f, 0.f, 0.f, 0.f};
            #pragma unroll
            for (int ks = 0; ks < 3; ++ks)
                #pragma unroll
                for (int nt = 0; nt < 2; ++nt) {
                    acc[nt] = __builtin_amdgcn_mfma_f32_16x16x32_bf16(ahi[ks], whi_r[nt][ks], acc[nt], 0, 0, 0);
                    acc[nt] = __builtin_amdgcn_mfma_f32_16x16x32_bf16(ahi[ks], wlo_r[nt][ks], acc[nt], 0, 0, 0);
                    acc[nt] = __builtin_amdgcn_mfma_f32_16x16x32_bf16(alo[ks], whi_r[nt][ks], acc[nt], 0, 0, 0);
                }
            #pragma unroll
            for (int nt = 0; nt < 2; ++nt)
                #pragma unroll
                for (int ri = 0; ri < 4; ++ri)
                    sp[nt] = fmaf(aj[ri], fmaxf(acc[nt][ri], 0.f), sp[nt]);
        }

        #pragma unroll
        for (int nt = 0; nt < 2; ++nt) {
            float s2 = sp[nt];
            s2 += __shfl_xor(s2, 16);
            s2 += __shfl_xor(s2, 32);
            if (lane < 16)
                svec_out[(size_t)b * 256 + (w * 2 + nt) * 16 + lrow] = s2;
        }
    }
}

// ===== kernel 3 (MFMA tail): pooled & fc1 via bf16x3 MFMA, 16 graphs/block =====
__global__ __launch_bounds__(512)
void k3_mfma(const float* __restrict__ svec,    // [B][256]
             const __bf16* __restrict__ W2fh,   // [16 nt][8 ks][64][8]
             const __bf16* __restrict__ W2fl,
             const __bf16* __restrict__ Wo1fh,  // [8 nt][8 ks][64][8]
             const __bf16* __restrict__ Wo1fl,
             const float* __restrict__ bo1,
             const float* __restrict__ Wo2,     // [2][128]
             const float* __restrict__ bo2,
             float* __restrict__ out, int B)
{
    __shared__ __align__(16) unsigned int Sp[16 * SPSTR];
    __shared__ __align__(16) unsigned int Pp[16 * SPSTR];
    __shared__ __align__(16) float Fl[16 * 132];

    const int t = threadIdx.x;
    const int b0 = blockIdx.x * 16;
    const int w = t >> 6, lane = t & 63;
    const int lrow = lane & 15, lkg = lane >> 4;

    for (int idx = t; idx < 4096; idx += 512) {
        int row = idx >> 8, col = idx & 255;
        float v = (b0 + row < B) ? svec[(size_t)(b0 + row) * 256 + col] : 0.0f;
        Sp[row * SPSTR + col] = pack_hl(v);
    }
    __syncthreads();

    {
        f32x4 acc[2];
        acc[0] = (f32x4){0.f, 0.f, 0.f, 0.f};
        acc[1] = (f32x4){0.f, 0.f, 0.f, 0.f};
        #pragma unroll
        for (int ks = 0; ks < 8; ++ks) {
            const uint4* src = (const uint4*)(Sp + lrow * SPSTR + ks * 32 + lkg * 8);
            uint4 a0 = src[0];
            uint4 a1 = src[1];
            u32x4v hw, lw;
            hw[0] = __builtin_amdgcn_perm(a0.y, a0.x, 0x05040100u);
            hw[1] = __builtin_amdgcn_perm(a0.w, a0.z, 0x05040100u);
            hw[2] = __builtin_amdgcn_perm(a1.y, a1.x, 0x05040100u);
            hw[3] = __builtin_amdgcn_perm(a1.w, a1.z, 0x05040100u);
            lw[0] = __builtin_amdgcn_perm(a0.y, a0.x, 0x07060302u);
            lw[1] = __builtin_amdgcn_perm(a0.w, a0.z, 0x07060302u);
            lw[2] = __builtin_amdgcn_perm(a1.y, a1.x, 0x07060302u);
            lw[3] = __builtin_amdgcn_perm(a1.w, a1.z, 0x07060302u);
            bf16x8 ahi = __builtin_bit_cast(bf16x8, hw);
            bf16x8 alo = __builtin_bit_cast(bf16x8, lw);
            #pragma unroll
            for (int nt = 0; nt < 2; ++nt) {
                int idx = (((w * 2 + nt) * 8 + ks) * 64 + lane) * 8;
                bf16x8 bhi = *(const bf16x8*)(W2fh + idx);
                bf16x8 blo = *(const bf16x8*)(W2fl + idx);
                acc[nt] = __builtin_amdgcn_mfma_f32_16x16x32_bf16(ahi, bhi, acc[nt], 0, 0, 0);
                acc[nt] = __builtin_amdgcn_mfma_f32_16x16x32_bf16(ahi, blo, acc[nt], 0, 0, 0);
                acc[nt] = __builtin_amdgcn_mfma_f32_16x16x32_bf16(alo, bhi, acc[nt], 0, 0, 0);
            }
        }
        #pragma unroll
        for (int nt = 0; nt < 2; ++nt)
            #pragma unroll
            for (int ri = 0; ri < 4; ++ri)
                Pp[(lkg * 4 + ri) * SPSTR + (w * 2 + nt) * 16 + lrow] = pack_hl(acc[nt][ri]);
    }
    __syncthreads();

    {
        f32x4 acc = (f32x4){0.f, 0.f, 0.f, 0.f};
        #pragma unroll
        for (int ks = 0; ks < 8; ++ks) {
            const uint4* src = (const uint4*)(Pp + lrow * SPSTR + ks * 32 + lkg * 8);
            uint4 a0 = src[0];
            uint4 a1 = src[1];
            u32x4v hw, lw;
            hw[0] = __builtin_amdgcn_perm(a0.y, a0.x, 0x05040100u);
            hw[1] = __builtin_amdgcn_perm(a0.w, a0.z, 0x05040100u);
            hw[2] = __builtin_amdgcn_perm(a1.y, a1.x, 0x05040100u);
            hw[3] = __builtin_amdgcn_perm(a1.w, a1.z, 0x05040100u);
            lw[0] = __builtin_amdgcn_perm(a0.y, a0.x, 0x07060302u);
            lw[1] = __builtin_amdgcn_perm(a0.w, a0.z, 0x07060302u);
            lw[2] = __builtin_amdgcn_perm(a1.y, a1.x, 0x07060302u);
            lw[3] = __builtin_amdgcn_perm(a1.w, a1.z, 0x07060302u);
            bf16x8 ahi = __builtin_bit_cast(bf16x8, hw);
            bf16x8 alo = __builtin_bit_cast(bf16x8, lw);
            int idx = ((w * 8 + ks) * 64 + lane) * 8;
            bf16x8 bhi = *(const bf16x8*)(Wo1fh + idx);
            bf16x8 blo = *(const bf16x8*)(Wo1fl + idx);
            acc = __builtin_amdgcn_mfma_f32_16x16x32_bf16(ahi, bhi, acc, 0, 0, 0);
            acc = __builtin_amdgcn_mfma_f32_16x16x32_bf16(ahi, blo, acc, 0, 0, 0);
            acc = __builtin_amdgcn_mfma_f32_16x16x32_bf16(alo, bhi, acc, 0, 0, 0);
        }
        float bias = bo1[w * 16 + lrow];
        #pragma unroll
        for (int ri = 0; ri < 4; ++ri)
            Fl[(lkg * 4 + ri) * 132 + w * 16 + lrow] = fmaxf(acc[ri] + bias, 0.f);
    }
    __syncthreads();

    if (t < 256) {
        int b = t >> 4, o = (t >> 3) & 1, q = t & 7;
        const float* wo = Wo2 + o * F1 + q * 16;
        const float* fv = Fl + b * 132 + q * 16;
        float p = 0.f;
        #pragma unroll
        for (int k = 0; k < 16; ++k) p = fmaf(wo[k], fv[k], p);
        p += __shfl_xor(p, 1);
        p += __shfl_xor(p, 2);
        p += __shfl_xor(p, 4);
        if (q == 0 && b0 + b < B) out[(size_t)(b0 + b) * 2 + o] = p + bo2[o];
    }
}

// ================= fallback: R9 monolithic kernel (ws too small) =================
__global__ __launch_bounds__(256)
void gcn_mono(const float* __restrict__ coh, const __bf16* __restrict__ Whi,
              const __bf16* __restrict__ Wlo, const int* __restrict__ ptab,
              const float* __restrict__ W2, const float* __restrict__ Wo1,
              const float* __restrict__ bo1, const float* __restrict__ Wo2,
              const float* __restrict__ bo2, float* __restrict__ out)
{
    __shared__ __align__(16) float A[JROWS * STR];
    __shared__ __align__(16) float svec_fc1[H1];
    __shared__ __align__(16) float pooled_dinv[H2];
    __shared__ __align__(16) float arow[96];
    float* dinv = pooled_dinv;
    float* pooled = pooled_dinv;
    const int b = blockIdx.x;
    const int t = threadIdx.x;
    const float* cb = coh + (size_t)b * NPAIR;

    for (int m = t; m < JROWS * 24; m += 256) {
        int i = m / 24, g = m - i * 24;
        *(float4*)&A[i * STR + g * 4] = make_float4(0.f, 0.f, 0.f, 0.f);
    }
    __syncthreads();
    for (int m = t; m < NPAIR; m += 256) {
        int p = ptab[m];
        int i = p >> 7, j = p & 127;
        float v = cb[m];
        A[i * STR + j] = v;
        A[j * STR + i] = v;
    }
    if (t < NN) {
        A[t * STR + t] = 1.0f;
        if (t < NREG) { A[NREG * STR + t] = 1.0f; A[t * STR + NREG] = 1.0f; }
    }
    __syncthreads();
    if (t < 256) dinv[t] = 0.0f;
    __syncthreads();
    if (t < NN) {
        const float4* row = (const float4*)&A[t * STR];
        float sx = 0.f, sy = 0.f, sz = 0.f, sw = 0.f;
        #pragma unroll
        for (int q = 0; q < 24; ++q) { float4 v = row[q]; sx += v.x; sy += v.y; sz += v.z; sw += v.w; }
        dinv[t] = 1.0f / sqrtf((sx + sy) + (sz + sw));
    }
    __syncthreads();
    for (int m = t; m < JROWS * 24; m += 256) {
        int i = m / 24;
        int c4 = (m - i * 24) * 4;
        float di = dinv[i];
        float4 dj = *(const float4*)&dinv[c4];
        float4 v = *(float4*)&A[i * STR + c4];
        v.x *= di * dj.x; v.y *= di * dj.y; v.z *= di * dj.z; v.w *= di * dj.w;
        *(float4*)&A[i * STR + c4] = v;
        if (i == NREG) *(float4*)&arow[c4] = v;
    }
    __syncthreads();
    for (int m = t; m < JROWS * 24; m += 256) {
        int i = m / 24;
        int c4 = (m - i * 24) * 4;
        float4 v = *(float4*)&A[i * STR + c4];
        uint4 p;
        p.x = pack_hl(v.x); p.y = pack_hl(v.y); p.z = pack_hl(v.z); p.w = pack_hl(v.w);
        *(uint4*)&A[i * STR + c4] = p;
    }
    __syncthreads();
    {
        const int w = t >> 6, lane = t & 63;
        const int lrow = lane & 15, lkg = lane >> 4;
        const unsigned int* Au = (const unsigned int*)A;
        bf16x8 whi_r[4][3], wlo_r[4][3];
        #pragma unroll
        for (int nt = 0; nt < 4; ++nt)
            #pragma unroll
            for (int ks = 0; ks < 3; ++ks) {
                int idx = (((w * 4 + nt) * 3 + ks) * 64 + lane) * 8;
                whi_r[nt][ks] = *(const bf16x8*)(Whi + idx);
                wlo_r[nt][ks] = *(const bf16x8*)(Wlo + idx);
            }
        float sp[4] = {0.f, 0.f, 0.f, 0.f};
        #pragma unroll 1
        for (int m = 0; m < 6; ++m) {
            bf16x8 ahi[3], alo[3];
            #pragma unroll
            for (int ks = 0; ks < 3; ++ks) {
                const uint4* src = (const uint4*)(Au + (m * 16 + lrow) * STR + ks * 32 + lkg * 8);
                uint4 a0 = src[0];
                uint4 a1 = src[1];
                u32x4v hw, lw;
                hw[0] = __builtin_amdgcn_perm(a0.y, a0.x, 0x05040100u);
                hw[1] = __builtin_amdgcn_perm(a0.w, a0.z, 0x05040100u);
                hw[2] = __builtin_amdgcn_perm(a1.y, a1.x, 0x05040100u);
                hw[3] = __builtin_amdgcn_perm(a1.w, a1.z, 0x05040100u);
                lw[0] = __builtin_amdgcn_perm(a0.y, a0.x, 0x07060302u);
                lw[1] = __builtin_amdgcn_perm(a0.w, a0.z, 0x07060302u);
                lw[2] = __builtin_amdgcn_perm(a1.y, a1.x, 0x07060302u);
                lw[3] = __builtin_amdgcn_perm(a1.w, a1.z, 0x07060302u);
                ahi[ks] = __builtin_bit_cast(bf16x8, hw);
                alo[ks] = __builtin_bit_cast(bf16x8, lw);
            }
            float aj[4];
            #pragma unroll
            for (int ri = 0; ri < 4; ++ri) aj[ri] = arow[m * 16 + lkg * 4 + ri];
            f32x4 acc[4];
            #pragma unroll
            for (int nt = 0; nt < 4; ++nt) acc[nt] = (f32x4){0.f, 0.f, 0.f, 0.f};
            #pragma unroll
            for (int ks = 0; ks < 3; ++ks)
                #pragma unroll
                for (int nt = 0; nt < 4; ++nt) {
                    acc[nt] = __builtin_amdgcn_mfma_f32_16x16x32_bf16(ahi[ks], whi_r[nt][ks], acc[nt], 0, 0, 0);
                    acc[nt] = __builtin_amdgcn_mfma_f32_16x16x32_bf16(ahi[ks], wlo_r[nt][ks], acc[nt], 0, 0, 0);
                    acc[nt] = __builtin_amdgcn_mfma_f32_16x16x32_bf16(alo[ks], whi_r[nt][ks], acc[nt], 0, 0, 0);
                }
            #pragma unroll
            for (int nt = 0; nt < 4; ++nt)
                #pragma unroll
                for (int ri = 0; ri < 4; ++ri)
                    sp[nt] = fmaf(aj[ri], fmaxf(acc[nt][ri], 0.f), sp[nt]);
        }
        __syncthreads();
        #pragma unroll
        for (int nt = 0; nt < 4; ++nt) {
            float s = sp[nt];
            s += __shfl_xor(s, 16);
            s += __shfl_xor(s, 32);
            if (lane < 16) svec_fc1[(w * 4 + nt) * 16 + lrow] = s;
        }
    }
    __syncthreads();
    {
        const float* w2r = W2 + t * H1;
        float p0 = 0.f, p1 = 0.f, p2 = 0.f, p3 = 0.f;
        #pragma unroll 8
        for (int qq = 0; qq < H1 / 4; ++qq) {
            float4 sv = ((const float4*)svec_fc1)[qq];
            float4 wv4 = *(const float4*)&w2r[qq * 4];
            p0 = fmaf(sv.x, wv4.x, p0); p1 = fmaf(sv.y, wv4.y, p1);
            p2 = fmaf(sv.z, wv4.z, p2); p3 = fmaf(sv.w, wv4.w, p3);
        }
        float pr = (p0 + p1) + (p2 + p3);
        __syncthreads();
        pooled[t] = pr;
    }
    __syncthreads();
    {
        float fr = 0.f;
        if (t < F1) {
            const float* wo1r = Wo1 + t * H2;
            float p0 = bo1[t], p1 = 0.f, p2 = 0.f, p3 = 0.f;
            #pragma unroll 8
            for (int qq = 0; qq < H2 / 4; ++qq) {
                float4 pv = ((const float4*)pooled)[qq];
                float4 wv4 = *(const float4*)&wo1r[qq * 4];
                p0 = fmaf(pv.x, wv4.x, p0); p1 = fmaf(pv.y, wv4.y, p1);
                p2 = fmaf(pv.z, wv4.z, p2); p3 = fmaf(pv.w, wv4.w, p3);
            }
            fr = fmaxf((p0 + p1) + (p2 + p3), 0.f);
        }
        __syncthreads();
        if (t < F1) svec_fc1[t] = fr;
    }
    __syncthreads();
    if (t < 64) {
        int o = t & 1;
        int f0 = t >> 1;
        const float* wo2r = Wo2 + o * F1;
        float p = 0.f;
        #pragma unroll
        for (int s = 0; s < 4; ++s) p = fmaf(wo2r[f0 + 32 * s], svec_fc1[f0 + 32 * s], p);
        p += __shfl_xor(p, 2); p += __shfl_xor(p, 4); p += __shfl_xor(p, 8);
        p += __shfl_xor(p, 16); p += __shfl_xor(p, 32);
        if (t < 2) out[(size_t)b * 2 + t] = p + bo2[t];
    }
}

extern "C" void kernel_launch(void* const* d_in, const int* in_sizes, int n_in,
                              void* d_out, int out_size, void* d_ws, size_t ws_size,
                              hipStream_t stream) {
    const float* coh = (const float*)d_in[0];
    const float* W1  = (const float*)d_in[1];
    const float* W2  = (const float*)d_in[2];
    const float* Wo1 = (const float*)d_in[3];
    const float* bo1 = (const float*)d_in[4];
    const float* Wo2 = (const float*)d_in[5];
    const float* bo2 = (const float*)d_in[6];
    float* outp = (float*)d_out;

    const int B = in_sizes[0] / NPAIR;            // 4096

    // ws layout
    __bf16* Whi   = (__bf16*)d_ws;                              // 49152 B
    __bf16* Wlo   = Whi + 24576;                                // 49152 B -> 98304
    int*    ptab  = (int*)((char*)d_ws + 98304);                // 16020 -> pad to 114688
    __bf16* W2fh  = (__bf16*)((char*)d_ws + 114688);            // 131072 -> 245760
    __bf16* W2fl  = (__bf16*)((char*)d_ws + 245760);            // 131072 -> 376832
    __bf16* Wo1fh = (__bf16*)((char*)d_ws + 376832);            // 65536 -> 442368
    __bf16* Wo1fl = (__bf16*)((char*)d_ws + 442368);            // 65536 -> 507904
    float*  svecw = (float*)((char*)d_ws + 507904);             // B*1024 B
    const size_t need = 507904 + (size_t)B * 1024;

    prep<<<256, 256, 0, stream>>>(W1, W2, Wo1, Whi, Wlo, ptab, W2fh, W2fl, Wo1fh, Wo1fl);

    if (ws_size >= need) {
        mk_build_gemm<<<B, 512, 0, stream>>>(coh, ptab, Whi, Wlo, svecw);
        k3_mfma<<<(B + 15) / 16, 512, 0, stream>>>(svecw, W2fh, W2fl, Wo1fh, Wo1fl,
                                                   bo1, Wo2, bo2, outp, B);
    } else {
        gcn_mono<<<B, 256, 0, stream>>>(coh, Whi, Wlo, ptab, W2, Wo1, bo1, Wo2, bo2, outp);
    }
}

// Round 23
// 95.554 us; speedup vs baseline: 1.0503x; 1.0503x over previous
//
#include <hip/hip_runtime.h>
#include <hip/hip_bf16.h>
#include <math.h>

#define NREG 90
#define NN 91
#define JROWS 96
#define STR 100           // A LDS stride (words), fp32 then packed u32 in place
#define NPAIR 4005
#define H1 256
#define H2 256
#define F1 128
#define SPSTR 260         // packed svec/pooled LDS stride (u32)

typedef __bf16 bf16x8 __attribute__((ext_vector_type(8)));
typedef float  f32x4  __attribute__((ext_vector_type(4)));
typedef unsigned int u32x4v __attribute__((ext_vector_type(4)));

__device__ __forceinline__ unsigned int pack_hl(float f) {
    __bf16 h = (__bf16)f;
    __bf16 l = (__bf16)(f - (float)h);
    unsigned short hb = __builtin_bit_cast(unsigned short, h);
    unsigned short lb = __builtin_bit_cast(unsigned short, l);
    return ((unsigned int)lb << 16) | (unsigned int)hb;
}

// ---- one-shot prep: W1/W2/Wo1 MFMA fragments (hi/lo) + pair table ----
__global__ void prep(const float* __restrict__ W1, const float* __restrict__ W2,
                     const float* __restrict__ Wo1,
                     __bf16* __restrict__ Whi, __bf16* __restrict__ Wlo,
                     int* __restrict__ ptab,
                     __bf16* __restrict__ W2fh, __bf16* __restrict__ W2fl,
                     __bf16* __restrict__ Wo1fh, __bf16* __restrict__ Wo1fl) {
    int t = blockIdx.x * 256 + threadIdx.x;       // 0..65535
    if (t < 24576) {                               // W1 frags [16 nt][3 ks][64][8]
        int e  = t & 7;
        int ln = (t >> 3) & 63;
        int g  = t >> 9;
        int nt = g / 3;
        int ks = g - nt * 3;
        int h = nt * 16 + (ln & 15);
        int k = ks * 32 + (ln >> 4) * 8 + e;
        float v = (k < NN) ? W1[h * NN + k] : 0.0f;
        __bf16 hb = (__bf16)v;
        __bf16 lb = (__bf16)(v - (float)hb);
        Whi[t] = hb;
        Wlo[t] = lb;
    }
    {                                              // W2 frags [16 nt][8 ks][64][8]
        int e  = t & 7;
        int ln = (t >> 3) & 63;
        int g2 = t >> 9;
        int nt = g2 >> 3, ks = g2 & 7;
        float v = W2[(nt * 16 + (ln & 15)) * 256 + ks * 32 + (ln >> 4) * 8 + e];
        __bf16 hb = (__bf16)v;
        __bf16 lb = (__bf16)(v - (float)hb);
        W2fh[t] = hb;
        W2fl[t] = lb;
    }
    if (t < 32768) {                               // Wo1 frags [8 nt][8 ks][64][8]
        int e  = t & 7;
        int ln = (t >> 3) & 63;
        int g2 = t >> 9;
        int nt = g2 >> 3, ks = g2 & 7;
        float v = Wo1[(nt * 16 + (ln & 15)) * 256 + ks * 32 + (ln >> 4) * 8 + e];
        __bf16 hb = (__bf16)v;
        __bf16 lb = (__bf16)(v - (float)hb);
        Wo1fh[t] = hb;
        Wo1fl[t] = lb;
    }
    if (t < NPAIR) {
        float disc = 32041.0f - 8.0f * (float)t;
        int i = (int)floorf((179.0f - sqrtf(disc)) * 0.5f);
        if (i < 0) i = 0;
        while (i > 0 && t < i * (179 - i) / 2) --i;
        while (t >= (i + 1) * (178 - i) / 2) ++i;
        int j = i + 1 + (t - i * (179 - i) / 2);
        ptab[t] = (i << 7) | j;
    }
}

// ========== merged kernel (512 thr, 8 waves): build A_hat + pack + MFMA -> svec ==========
__global__ __launch_bounds__(512)
void mk_build_gemm(const float* __restrict__ coh,    // [B, 4005]
                   const int*   __restrict__ ptab,
                   const __bf16* __restrict__ Whi,   // [16][3][64][8]
                   const __bf16* __restrict__ Wlo,
                   float* __restrict__ svec_out)     // [B][256]
{
    __shared__ __align__(16) float A[JROWS * STR];   // 38400 B
    __shared__ __align__(16) float dinv[128];
    __shared__ __align__(16) float arow[96];

    const int b = blockIdx.x;
    const int t = threadIdx.x;
    const int w = t >> 6, lane = t & 63;
    const float* cb = coh + (size_t)b * NPAIR;

    bf16x8 whi_r[2][3], wlo_r[2][3];
    #pragma unroll
    for (int nt = 0; nt < 2; ++nt)
        #pragma unroll
        for (int ks = 0; ks < 3; ++ks) {
            int idx = (((w * 2 + nt) * 3 + ks) * 64 + lane) * 8;
            whi_r[nt][ks] = *(const bf16x8*)(Whi + idx);
            wlo_r[nt][ks] = *(const bf16x8*)(Wlo + idx);
        }

    for (int m4 = t; m4 < NPAIR / 4; m4 += 512) {
        int4 p4 = ((const int4*)ptab)[m4];
        float v0 = cb[4 * m4 + 0];
        float v1 = cb[4 * m4 + 1];
        float v2 = cb[4 * m4 + 2];
        float v3 = cb[4 * m4 + 3];
        int i0 = p4.x >> 7, j0 = p4.x & 127;
        int i1 = p4.y >> 7, j1 = p4.y & 127;
        int i2 = p4.z >> 7, j2 = p4.z & 127;
        int i3 = p4.w >> 7, j3 = p4.w & 127;
        A[i0 * STR + j0] = v0; A[j0 * STR + i0] = v0;
        A[i1 * STR + j1] = v1; A[j1 * STR + i1] = v1;
        A[i2 * STR + j2] = v2; A[j2 * STR + i2] = v2;
        A[i3 * STR + j3] = v3; A[j3 * STR + i3] = v3;
    }
    if (t == 0) {
        int p = ptab[NPAIR - 1];
        int i = p >> 7, j = p & 127;
        float v = cb[NPAIR - 1];
        A[i * STR + j] = v;
        A[j * STR + i] = v;
    }
    if (t < NN) {
        A[t * STR + t] = 1.0f;
        if (t < NREG) {
            A[NREG * STR + t] = 1.0f;
            A[t * STR + NREG] = 1.0f;
        }
        A[t * STR + 91] = 0.0f;
        A[t * STR + 92] = 0.0f;
        A[t * STR + 93] = 0.0f;
        A[t * STR + 94] = 0.0f;
        A[t * STR + 95] = 0.0f;
    }
    if (t >= 128 && t < 128 + 5 * 24) {
        int m = t - 128;
        int i = 91 + m / 24;
        int c4 = (m - (m / 24) * 24) * 4;
        *(float4*)&A[i * STR + c4] = make_float4(0.f, 0.f, 0.f, 0.f);
    }
    if (t >= 256 && t < 384) dinv[t - 256] = 0.0f;
    __syncthreads();

    if (t < NN) {
        const float4* row = (const float4*)&A[t * STR];
        float sx = 0.f, sy = 0.f, sz = 0.f, sw = 0.f;
        #pragma unroll
        for (int q = 0; q < 24; ++q) {
            float4 v = row[q];
            sx += v.x; sy += v.y; sz += v.z; sw += v.w;
        }
        dinv[t] = 1.0f / sqrtf((sx + sy) + (sz + sw));
    }
    __syncthreads();

    for (int m = t; m < JROWS * 24; m += 512) {
        int i = m / 24;
        int c4 = (m - i * 24) * 4;
        float di = dinv[i];
        float4 dj = *(const float4*)&dinv[c4];
        float4 v = *(float4*)&A[i * STR + c4];
        v.x *= di * dj.x; v.y *= di * dj.y; v.z *= di * dj.z; v.w *= di * dj.w;
        if (i == NREG && c4 < 96) *(float4*)&arow[c4] = v;
        uint4 p;
        p.x = pack_hl(v.x); p.y = pack_hl(v.y);
        p.z = pack_hl(v.z); p.w = pack_hl(v.w);
        *(uint4*)&A[i * STR + c4] = p;
    }
    __syncthreads();

    {
        const int lrow = lane & 15, lkg = lane >> 4;
        const unsigned int* Au = (const unsigned int*)A;

        float sp[2] = {0.f, 0.f};

        #pragma unroll
        for (int m = 0; m < 6; ++m) {
            bf16x8 ahi[3], alo[3];
            #pragma unroll
            for (int ks = 0; ks < 3; ++ks) {
                const uint4* src = (const uint4*)(Au + (m * 16 + lrow) * STR + ks * 32 + lkg * 8);
                uint4 a0 = src[0];
                uint4 a1 = src[1];
                u32x4v hw, lw;
                hw[0] = __builtin_amdgcn_perm(a0.y, a0.x, 0x05040100u);
                hw[1] = __builtin_amdgcn_perm(a0.w, a0.z, 0x05040100u);
                hw[2] = __builtin_amdgcn_perm(a1.y, a1.x, 0x05040100u);
                hw[3] = __builtin_amdgcn_perm(a1.w, a1.z, 0x05040100u);
                lw[0] = __builtin_amdgcn_perm(a0.y, a0.x, 0x07060302u);
                lw[1] = __builtin_amdgcn_perm(a0.w, a0.z, 0x07060302u);
                lw[2] = __builtin_amdgcn_perm(a1.y, a1.x, 0x07060302u);
                lw[3] = __builtin_amdgcn_perm(a1.w, a1.z, 0x07060302u);
                ahi[ks] = __builtin_bit_cast(bf16x8, hw);
                alo[ks] = __builtin_bit_cast(bf16x8, lw);
            }
            float aj[4];
            #pragma unroll
            for (int ri = 0; ri < 4; ++ri)
                aj[ri] = arow[m * 16 + lkg * 4 + ri];

            f32x4 acc[2];
            acc[0] = (f32x4){0.f, 0.f, 0.f, 0.f};
            acc[1] = (f32x4){0.f, 0.f, 0.f, 0.f};
            #pragma unroll
            for (int ks = 0; ks < 3; ++ks)
                #pragma unroll
                for (int nt = 0; nt < 2; ++nt) {
                    acc[nt] = __builtin_amdgcn_mfma_f32_16x16x32_bf16(ahi[ks], whi_r[nt][ks], acc[nt], 0, 0, 0);
                    acc[nt] = __builtin_amdgcn_mfma_f32_16x16x32_bf16(ahi[ks], wlo_r[nt][ks], acc[nt], 0, 0, 0);
                    acc[nt] = __builtin_amdgcn_mfma_f32_16x16x32_bf16(alo[ks], whi_r[nt][ks], acc[nt], 0, 0, 0);
                }
            #pragma unroll
            for (int nt = 0; nt < 2; ++nt)
                #pragma unroll
                for (int ri = 0; ri < 4; ++ri)
                    sp[nt] = fmaf(aj[ri], fmaxf(acc[nt][ri], 0.f), sp[nt]);
        }

        #pragma unroll
        for (int nt = 0; nt < 2; ++nt) {
            float s = sp[nt];
            s += __shfl_xor(s, 16);
            s += __shfl_xor(s, 32);
            if (lane < 16)
                svec_out[(size_t)b * 256 + (w * 2 + nt) * 16 + lrow] = s;
        }
    }
}

// ===== kernel 3 (MFMA tail): pooled & fc1 via bf16x3 MFMA, 16 graphs/block =====
__global__ __launch_bounds__(512)
void k3_mfma(const float* __restrict__ svec,    // [B][256]
             const __bf16* __restrict__ W2fh,   // [16 nt][8 ks][64][8]
             const __bf16* __restrict__ W2fl,
             const __bf16* __restrict__ Wo1fh,  // [8 nt][8 ks][64][8]
             const __bf16* __restrict__ Wo1fl,
             const float* __restrict__ bo1,
             const float* __restrict__ Wo2,     // [2][128]
             const float* __restrict__ bo2,
             float* __restrict__ out, int B)
{
    __shared__ __align__(16) unsigned int Sp[16 * SPSTR];
    __shared__ __align__(16) unsigned int Pp[16 * SPSTR];
    __shared__ __align__(16) float Fl[16 * 132];

    const int t = threadIdx.x;
    const int b0 = blockIdx.x * 16;
    const int w = t >> 6, lane = t & 63;
    const int lrow = lane & 15, lkg = lane >> 4;

    for (int idx = t; idx < 4096; idx += 512) {
        int row = idx >> 8, col = idx & 255;
        float v = (b0 + row < B) ? svec[(size_t)(b0 + row) * 256 + col] : 0.0f;
        Sp[row * SPSTR + col] = pack_hl(v);
    }
    __syncthreads();

    {
        f32x4 acc[2];
        acc[0] = (f32x4){0.f, 0.f, 0.f, 0.f};
        acc[1] = (f32x4){0.f, 0.f, 0.f, 0.f};
        #pragma unroll
        for (int ks = 0; ks < 8; ++ks) {
            const uint4* src = (const uint4*)(Sp + lrow * SPSTR + ks * 32 + lkg * 8);
            uint4 a0 = src[0];
            uint4 a1 = src[1];
            u32x4v hw, lw;
            hw[0] = __builtin_amdgcn_perm(a0.y, a0.x, 0x05040100u);
            hw[1] = __builtin_amdgcn_perm(a0.w, a0.z, 0x05040100u);
            hw[2] = __builtin_amdgcn_perm(a1.y, a1.x, 0x05040100u);
            hw[3] = __builtin_amdgcn_perm(a1.w, a1.z, 0x05040100u);
            lw[0] = __builtin_amdgcn_perm(a0.y, a0.x, 0x07060302u);
            lw[1] = __builtin_amdgcn_perm(a0.w, a0.z, 0x07060302u);
            lw[2] = __builtin_amdgcn_perm(a1.y, a1.x, 0x07060302u);
            lw[3] = __builtin_amdgcn_perm(a1.w, a1.z, 0x07060302u);
            bf16x8 ahi = __builtin_bit_cast(bf16x8, hw);
            bf16x8 alo = __builtin_bit_cast(bf16x8, lw);
            #pragma unroll
            for (int nt = 0; nt < 2; ++nt) {
                int idx = (((w * 2 + nt) * 8 + ks) * 64 + lane) * 8;
                bf16x8 bhi = *(const bf16x8*)(W2fh + idx);
                bf16x8 blo = *(const bf16x8*)(W2fl + idx);
                acc[nt] = __builtin_amdgcn_mfma_f32_16x16x32_bf16(ahi, bhi, acc[nt], 0, 0, 0);
                acc[nt] = __builtin_amdgcn_mfma_f32_16x16x32_bf16(ahi, blo, acc[nt], 0, 0, 0);
                acc[nt] = __builtin_amdgcn_mfma_f32_16x16x32_bf16(alo, bhi, acc[nt], 0, 0, 0);
            }
        }
        #pragma unroll
        for (int nt = 0; nt < 2; ++nt)
            #pragma unroll
            for (int ri = 0; ri < 4; ++ri)
                Pp[(lkg * 4 + ri) * SPSTR + (w * 2 + nt) * 16 + lrow] = pack_hl(acc[nt][ri]);
    }
    __syncthreads();

    {
        f32x4 acc = (f32x4){0.f, 0.f, 0.f, 0.f};
        #pragma unroll
        for (int ks = 0; ks < 8; ++ks) {
            const uint4* src = (const uint4*)(Pp + lrow * SPSTR + ks * 32 + lkg * 8);
            uint4 a0 = src[0];
            uint4 a1 = src[1];
            u32x4v hw, lw;
            hw[0] = __builtin_amdgcn_perm(a0.y, a0.x, 0x05040100u);
            hw[1] = __builtin_amdgcn_perm(a0.w, a0.z, 0x05040100u);
            hw[2] = __builtin_amdgcn_perm(a1.y, a1.x, 0x05040100u);
            hw[3] = __builtin_amdgcn_perm(a1.w, a1.z, 0x05040100u);
            lw[0] = __builtin_amdgcn_perm(a0.y, a0.x, 0x07060302u);
            lw[1] = __builtin_amdgcn_perm(a0.w, a0.z, 0x07060302u);
            lw[2] = __builtin_amdgcn_perm(a1.y, a1.x, 0x07060302u);
            lw[3] = __builtin_amdgcn_perm(a1.w, a1.z, 0x07060302u);
            bf16x8 ahi = __builtin_bit_cast(bf16x8, hw);
            bf16x8 alo = __builtin_bit_cast(bf16x8, lw);
            int idx = ((w * 8 + ks) * 64 + lane) * 8;
            bf16x8 bhi = *(const bf16x8*)(Wo1fh + idx);
            bf16x8 blo = *(const bf16x8*)(Wo1fl + idx);
            acc = __builtin_amdgcn_mfma_f32_16x16x32_bf16(ahi, bhi, acc, 0, 0, 0);
            acc = __builtin_amdgcn_mfma_f32_16x16x32_bf16(ahi, blo, acc, 0, 0, 0);
            acc = __builtin_amdgcn_mfma_f32_16x16x32_bf16(alo, bhi, acc, 0, 0, 0);
        }
        float bias = bo1[w * 16 + lrow];
        #pragma unroll
        for (int ri = 0; ri < 4; ++ri)
            Fl[(lkg * 4 + ri) * 132 + w * 16 + lrow] = fmaxf(acc[ri] + bias, 0.f);
    }
    __syncthreads();

    if (t < 256) {
        int b = t >> 4, o = (t >> 3) & 1, q = t & 7;
        const float* wo = Wo2 + o * F1 + q * 16;
        const float* fv = Fl + b * 132 + q * 16;
        float p = 0.f;
        #pragma unroll
        for (int k = 0; k < 16; ++k) p = fmaf(wo[k], fv[k], p);
        p += __shfl_xor(p, 1);
        p += __shfl_xor(p, 2);
        p += __shfl_xor(p, 4);
        if (q == 0 && b0 + b < B) out[(size_t)(b0 + b) * 2 + o] = p + bo2[o];
    }
}

// ================= fallback: R9 monolithic kernel (ws too small) =================
__global__ __launch_bounds__(256)
void gcn_mono(const float* __restrict__ coh, const __bf16* __restrict__ Whi,
              const __bf16* __restrict__ Wlo, const int* __restrict__ ptab,
              const float* __restrict__ W2, const float* __restrict__ Wo1,
              const float* __restrict__ bo1, const float* __restrict__ Wo2,
              const float* __restrict__ bo2, float* __restrict__ out)
{
    __shared__ __align__(16) float A[JROWS * STR];
    __shared__ __align__(16) float svec_fc1[H1];
    __shared__ __align__(16) float pooled_dinv[H2];
    __shared__ __align__(16) float arow[96];
    float* dinv = pooled_dinv;
    float* pooled = pooled_dinv;
    const int b = blockIdx.x;
    const int t = threadIdx.x;
    const float* cb = coh + (size_t)b * NPAIR;

    for (int m = t; m < JROWS * 24; m += 256) {
        int i = m / 24, g = m - i * 24;
        *(float4*)&A[i * STR + g * 4] = make_float4(0.f, 0.f, 0.f, 0.f);
    }
    __syncthreads();
    for (int m = t; m < NPAIR; m += 256) {
        int p = ptab[m];
        int i = p >> 7, j = p & 127;
        float v = cb[m];
        A[i * STR + j] = v;
        A[j * STR + i] = v;
    }
    if (t < NN) {
        A[t * STR + t] = 1.0f;
        if (t < NREG) { A[NREG * STR + t] = 1.0f; A[t * STR + NREG] = 1.0f; }
    }
    __syncthreads();
    if (t < 256) dinv[t] = 0.0f;
    __syncthreads();
    if (t < NN) {
        const float4* row = (const float4*)&A[t * STR];
        float sx = 0.f, sy = 0.f, sz = 0.f, sw = 0.f;
        #pragma unroll
        for (int q = 0; q < 24; ++q) { float4 v = row[q]; sx += v.x; sy += v.y; sz += v.z; sw += v.w; }
        dinv[t] = 1.0f / sqrtf((sx + sy) + (sz + sw));
    }
    __syncthreads();
    for (int m = t; m < JROWS * 24; m += 256) {
        int i = m / 24;
        int c4 = (m - i * 24) * 4;
        float di = dinv[i];
        float4 dj = *(const float4*)&dinv[c4];
        float4 v = *(float4*)&A[i * STR + c4];
        v.x *= di * dj.x; v.y *= di * dj.y; v.z *= di * dj.z; v.w *= di * dj.w;
        *(float4*)&A[i * STR + c4] = v;
        if (i == NREG) *(float4*)&arow[c4] = v;
    }
    __syncthreads();
    for (int m = t; m < JROWS * 24; m += 256) {
        int i = m / 24;
        int c4 = (m - i * 24) * 4;
        float4 v = *(float4*)&A[i * STR + c4];
        uint4 p;
        p.x = pack_hl(v.x); p.y = pack_hl(v.y); p.z = pack_hl(v.z); p.w = pack_hl(v.w);
        *(uint4*)&A[i * STR + c4] = p;
    }
    __syncthreads();
    {
        const int w = t >> 6, lane = t & 63;
        const int lrow = lane & 15, lkg = lane >> 4;
        const unsigned int* Au = (const unsigned int*)A;
        bf16x8 whi_r[4][3], wlo_r[4][3];
        #pragma unroll
        for (int nt = 0; nt < 4; ++nt)
            #pragma unroll
            for (int ks = 0; ks < 3; ++ks) {
                int idx = (((w * 4 + nt) * 3 + ks) * 64 + lane) * 8;
                whi_r[nt][ks] = *(const bf16x8*)(Whi + idx);
                wlo_r[nt][ks] = *(const bf16x8*)(Wlo + idx);
            }
        float sp[4] = {0.f, 0.f, 0.f, 0.f};
        #pragma unroll 1
        for (int m = 0; m < 6; ++m) {
            bf16x8 ahi[3], alo[3];
            #pragma unroll
            for (int ks = 0; ks < 3; ++ks) {
                const uint4* src = (const uint4*)(Au + (m * 16 + lrow) * STR + ks * 32 + lkg * 8);
                uint4 a0 = src[0];
                uint4 a1 = src[1];
                u32x4v hw, lw;
                hw[0] = __builtin_amdgcn_perm(a0.y, a0.x, 0x05040100u);
                hw[1] = __builtin_amdgcn_perm(a0.w, a0.z, 0x05040100u);
                hw[2] = __builtin_amdgcn_perm(a1.y, a1.x, 0x05040100u);
                hw[3] = __builtin_amdgcn_perm(a1.w, a1.z, 0x05040100u);
                lw[0] = __builtin_amdgcn_perm(a0.y, a0.x, 0x07060302u);
                lw[1] = __builtin_amdgcn_perm(a0.w, a0.z, 0x07060302u);
                lw[2] = __builtin_amdgcn_perm(a1.y, a1.x, 0x07060302u);
                lw[3] = __builtin_amdgcn_perm(a1.w, a1.z, 0x07060302u);
                ahi[ks] = __builtin_bit_cast(bf16x8, hw);
                alo[ks] = __builtin_bit_cast(bf16x8, lw);
            }
            float aj[4];
            #pragma unroll
            for (int ri = 0; ri < 4; ++ri) aj[ri] = arow[m * 16 + lkg * 4 + ri];
            f32x4 acc[4];
            #pragma unroll
            for (int nt = 0; nt < 4; ++nt) acc[nt] = (f32x4){0.f, 0.f, 0.f, 0.f};
            #pragma unroll
            for (int ks = 0; ks < 3; ++ks)
                #pragma unroll
                for (int nt = 0; nt < 4; ++nt) {
                    acc[nt] = __builtin_amdgcn_mfma_f32_16x16x32_bf16(ahi[ks], whi_r[nt][ks], acc[nt], 0, 0, 0);
                    acc[nt] = __builtin_amdgcn_mfma_f32_16x16x32_bf16(ahi[ks], wlo_r[nt][ks], acc[nt], 0, 0, 0);
                    acc[nt] = __builtin_amdgcn_mfma_f32_16x16x32_bf16(alo[ks], whi_r[nt][ks], acc[nt], 0, 0, 0);
                }
            #pragma unroll
            for (int nt = 0; nt < 4; ++nt)
                #pragma unroll
                for (int ri = 0; ri < 4; ++ri)
                    sp[nt] = fmaf(aj[ri], fmaxf(acc[nt][ri], 0.f), sp[nt]);
        }
        __syncthreads();
        #pragma unroll
        for (int nt = 0; nt < 4; ++nt) {
            float s = sp[nt];
            s += __shfl_xor(s, 16);
            s += __shfl_xor(s, 32);
            if (lane < 16) svec_fc1[(w * 4 + nt) * 16 + lrow] = s;
        }
    }
    __syncthreads();
    {
        const float* w2r = W2 + t * H1;
        float p0 = 0.f, p1 = 0.f, p2 = 0.f, p3 = 0.f;
        #pragma unroll 8
        for (int qq = 0; qq < H1 / 4; ++qq) {
            float4 sv = ((const float4*)svec_fc1)[qq];
            float4 wv4 = *(const float4*)&w2r[qq * 4];
            p0 = fmaf(sv.x, wv4.x, p0); p1 = fmaf(sv.y, wv4.y, p1);
            p2 = fmaf(sv.z, wv4.z, p2); p3 = fmaf(sv.w, wv4.w, p3);
        }
        float pr = (p0 + p1) + (p2 + p3);
        __syncthreads();
        pooled[t] = pr;
    }
    __syncthreads();
    {
        float fr = 0.f;
        if (t < F1) {
            const float* wo1r = Wo1 + t * H2;
            float p0 = bo1[t], p1 = 0.f, p2 = 0.f, p3 = 0.f;
            #pragma unroll 8
            for (int qq = 0; qq < H2 / 4; ++qq) {
                float4 pv = ((const float4*)pooled)[qq];
                float4 wv4 = *(const float4*)&wo1r[qq * 4];
                p0 = fmaf(pv.x, wv4.x, p0); p1 = fmaf(pv.y, wv4.y, p1);
                p2 = fmaf(pv.z, wv4.z, p2); p3 = fmaf(pv.w, wv4.w, p3);
            }
            fr = fmaxf((p0 + p1) + (p2 + p3), 0.f);
        }
        __syncthreads();
        if (t < F1) svec_fc1[t] = fr;
    }
    __syncthreads();
    if (t < 64) {
        int o = t & 1;
        int f0 = t >> 1;
        const float* wo2r = Wo2 + o * F1;
        float p = 0.f;
        #pragma unroll
        for (int s = 0; s < 4; ++s) p = fmaf(wo2r[f0 + 32 * s], svec_fc1[f0 + 32 * s], p);
        p += __shfl_xor(p, 2); p += __shfl_xor(p, 4); p += __shfl_xor(p, 8);
        p += __shfl_xor(p, 16); p += __shfl_xor(p, 32);
        if (t < 2) out[(size_t)b * 2 + t] = p + bo2[t];
    }
}

extern "C" void kernel_launch(void* const* d_in, const int* in_sizes, int n_in,
                              void* d_out, int out_size, void* d_ws, size_t ws_size,
                              hipStream_t stream) {
    const float* coh = (const float*)d_in[0];
    const float* W1  = (const float*)d_in[1];
    const float* W2  = (const float*)d_in[2];
    const float* Wo1 = (const float*)d_in[3];
    const float* bo1 = (const float*)d_in[4];
    const float* Wo2 = (const float*)d_in[5];
    const float* bo2 = (const float*)d_in[6];
    float* outp = (float*)d_out;

    const int B = in_sizes[0] / NPAIR;            // 4096

    // ws layout
    __bf16* Whi   = (__bf16*)d_ws;                              // 49152 B
    __bf16* Wlo   = Whi + 24576;                                // 49152 B -> 98304
    int*    ptab  = (int*)((char*)d_ws + 98304);                // 16020 -> pad to 114688
    __bf16* W2fh  = (__bf16*)((char*)d_ws + 114688);            // 131072 -> 245760
    __bf16* W2fl  = (__bf16*)((char*)d_ws + 245760);            // 131072 -> 376832
    __bf16* Wo1fh = (__bf16*)((char*)d_ws + 376832);            // 65536 -> 442368
    __bf16* Wo1fl = (__bf16*)((char*)d_ws + 442368);            // 65536 -> 507904
    float*  svecw = (float*)((char*)d_ws + 507904);             // B*1024 B
    const size_t need = 507904 + (size_t)B * 1024;

    prep<<<256, 256, 0, stream>>>(W1, W2, Wo1, Whi, Wlo, ptab, W2fh, W2fl, Wo1fh, Wo1fl);

    if (ws_size >= need) {
        mk_build_gemm<<<B, 512, 0, stream>>>(coh, ptab, Whi, Wlo, svecw);
        k3_mfma<<<(B + 15) / 16, 512, 0, stream>>>(svecw, W2fh, W2fl, Wo1fh, Wo1fl,
                                                   bo1, Wo2, bo2, outp, B);
    } else {
        gcn_mono<<<B, 256, 0, stream>>>(coh, Whi, Wlo, ptab, W2, Wo1, bo1, Wo2, bo2, outp);
    }
}